// Round 4
// baseline (484.441 us; speedup 1.0000x reference)
//
#include <hip/hip_runtime.h>

// FlowNetC correlation, MI355X/gfx950. fp32 in/out, f16 MFMA (f32 accum).
// B=8 C=256 H=64 W=96; 21x21 displacements step 2, pad 20, scale 1/C.
//
// Block = (b, 4 y-rows, 4 dy); 512 thr / 8 waves; wave = (y_l, dyg).
// Parity split x = 2x'+par; per (y,dy,par): S[x'][w'] = sum_c A[c][x']B[c][w'],
// j = w'-x' in [0,21), w' = x'_2 + 10 (slots 0..9 / 58..79 are zero pads).
// v_mfma_f32_16x16x16f16 (direct call; host pass resolves via aux-target).
// K chunked 16 ch x 16 chunks, single-buffered LDS.
//
// R3 vs R2: bijective row perm PHYS (low-3-bit rotate) so each unrolled
// ds_write_b128 spans all 32 banks (was 16 -> 2x write conflict); applied
// identically on write+read. __launch_bounds__(512,2) pins VGPR<=256.

#define ND 21
#define CIN 6144           // 64*96
#define BIN 1572864        // 256*64*96
#define BOUT (441 * 6144)

typedef _Float16 f16;
typedef _Float16 f16x4 __attribute__((ext_vector_type(4)));
typedef _Float16 f16x8 __attribute__((ext_vector_type(8)));
typedef float    f32x4 __attribute__((ext_vector_type(4)));

// LDS: rows of 32B (16 f16 = 16 k). Logical row R -> physical row PHYS(R)
// (bijection within each 8-row group: bits (b2,b1,b0) -> (b0,b2,b1)).
// data(R,k) at f16-index P*16 + chunk*8 + (k&7), chunk = (k>>3) ^ ((P>>2)&1).
// s1 rows 0..383:    R = (y*2+par)*48 + x'          (x' 0..47)
// s2 rows 384..1983: R = 384 + (r*2+par)*80 + w'    (w' 0..79; 0..9 & 58..79 pad)
#define S2R0 384
#define NROWS 1984   // 1984*32 = 63488 B

__device__ __forceinline__ int PHYS(int R) {
    return ((R >> 1) & 3) | ((R & 1) << 2) | (R & ~7);
}

__global__ __launch_bounds__(512, 2) void corr_kernel(const float* __restrict__ in1,
                                                      const float* __restrict__ in2,
                                                      float* __restrict__ out) {
    __shared__ __align__(16) unsigned char smem[NROWS * 32];
    f16*   S    = (f16*)smem;
    float* ebuf = (float*)smem;   // epilogue reuse: 8 regions x 11 x 96 f32 = 33792 B

    const int tid = threadIdx.x;
    // XCD-bijective swizzle: 768 = 8 XCDs x 96; each XCD owns one batch b.
    const int bid = (blockIdx.x & 7) * 96 + (blockIdx.x >> 3);
    const int b   = bid / 96;
    const int r0_ = bid % 96;
    const int yt  = r0_ / 6;
    const int iyt = r0_ % 6;
    const int y0       = yt * 4;
    const int iy_base  = iyt * 4;
    const int row_base = y0 + 2 * iy_base - 20;   // in2 global row for local r: row_base + r

    const int wid  = tid >> 6;
    const int lane = tid & 63;
    const int y_l  = wid & 3;
    const int dyg  = wid >> 2;     // 0..1 ; dy_local = dyg*2 + il in 0..3
    const int g    = lane >> 4;    // 0..3
    const int c16  = lane & 15;
    const bool wave_active = (iy_base + dyg * 2) < ND;

    // zero all LDS once (covers s2 pad rows which staging never rewrites)
    for (int u = tid; u < NROWS * 8; u += 512) ((int*)smem)[u] = 0;

    f32x4 acc[2][2][3][3];   // [par][il][mt][d]
    const f32x4 z4 = {0.f, 0.f, 0.f, 0.f};
#pragma unroll
    for (int p = 0; p < 2; ++p)
#pragma unroll
        for (int il = 0; il < 2; ++il)
#pragma unroll
            for (int mt = 0; mt < 3; ++mt)
#pragma unroll
                for (int d = 0; d < 3; ++d) acc[p][il][mt][d] = z4;

    const float* in1b = in1 + (size_t)b * BIN + y0 * 96;
    const float* in2b = in2 + (size_t)b * BIN;

    for (int ch = 0; ch < 16; ++ch) {
        const int c0 = ch * 16;
        __syncthreads();   // prev compute done before overwrite (also orders zero-init)

        // ---- staging: 672 tasks; task = (rows-quad, k-half). 8 coalesced float4
        // loads across k -> register transpose -> 4 perm+swizzled ds_write_b128.
        for (int task = tid; task < 672; task += 512) {
            int x4, kh, rowbase, ps;
            const float* gp;
            bool valid;
            if (task < 192) {                      // in1: (y, x4, kh)
                const int y = task / 48, rem = task % 48;
                x4 = rem >> 1; kh = rem & 1;
                gp = in1b + y * 96 + x4 * 4;
                rowbase = y * 96 + 2 * x4;         // (y*2+0)*48 + 2*x4
                ps = 48; valid = true;
            } else {                               // in2: (r, x4, kh)
                const int t2 = task - 192;
                const int r = t2 / 48, rem = t2 % 48;
                x4 = rem >> 1; kh = rem & 1;
                const int gy = row_base + r;
                valid = (gy >= 0) && (gy < 64);
                const int gyc = valid ? gy : 0;
                gp = in2b + gyc * 96 + x4 * 4;
                rowbase = S2R0 + r * 160 + 10 + 2 * x4;   // + par*80 + dx
                ps = 80;
            }
            float4 v[8];
#pragma unroll
            for (int j = 0; j < 8; ++j) {
                if (valid) v[j] = *(const float4*)(gp + (c0 + kh * 8 + j) * CIN);
                else       v[j] = make_float4(0.f, 0.f, 0.f, 0.f);
            }
            f16x8 rv[4];   // rv[i]: i = par + 2*dx
#pragma unroll
            for (int j = 0; j < 8; ++j) {
                rv[0][j] = (f16)v[j].x; rv[1][j] = (f16)v[j].y;
                rv[2][j] = (f16)v[j].z; rv[3][j] = (f16)v[j].w;
            }
#pragma unroll
            for (int i = 0; i < 4; ++i) {
                const int P = PHYS(rowbase + (i & 1) * ps + (i >> 1));
                *(f16x8*)&S[P * 16 + ((kh ^ ((P >> 2) & 1)) << 3)] = rv[i];
            }
        }
        __syncthreads();

        // ---- compute: frags via single ds_read_b64 each (perm+swizzled) ----
        if (wave_active) {
#pragma unroll
            for (int par = 0; par < 2; ++par) {
                f16x4 a[3];
#pragma unroll
                for (int mt = 0; mt < 3; ++mt) {
                    const int P = PHYS((y_l * 2 + par) * 48 + mt * 16 + c16);
                    a[mt] = *(const f16x4*)&S[P * 16 + (((g >> 1) ^ ((P >> 2) & 1)) << 3) +
                                              ((g & 1) << 2)];
                }
#pragma unroll
                for (int il = 0; il < 2; ++il) {
                    const int r = y_l + 2 * (dyg * 2 + il);
                    f16x4 bf[5];
#pragma unroll
                    for (int wt = 0; wt < 5; ++wt) {
                        const int P = PHYS(S2R0 + (r * 2 + par) * 80 + wt * 16 + c16);
                        bf[wt] = *(const f16x4*)&S[P * 16 + (((g >> 1) ^ ((P >> 2) & 1)) << 3) +
                                                   ((g & 1) << 2)];
                    }
#pragma unroll
                    for (int mt = 0; mt < 3; ++mt)
#pragma unroll
                        for (int d = 0; d < 3; ++d)
                            acc[par][il][mt][d] = __builtin_amdgcn_mfma_f32_16x16x16f16(
                                a[mt], bf[mt + d], acc[par][il][mt][d], 0, 0, 0);
                }
            }
        }
    }

    // ---- epilogue: diag-extract via LDS, coalesced stores ----
    __syncthreads();
    const float scale = 1.0f / 256.0f;
#pragma unroll
    for (int q = 0; q < 2; ++q) {
        const int j0 = q * 11;
        const int nj = q ? 10 : 11;
#pragma unroll
        for (int il = 0; il < 2; ++il) {
            const int iy = iy_base + dyg * 2 + il;
            if (iy < ND) {
#pragma unroll
                for (int par = 0; par < 2; ++par)
#pragma unroll
                    for (int mt = 0; mt < 3; ++mt)
#pragma unroll
                        for (int d = 0; d < 3; ++d)
#pragma unroll
                            for (int rg = 0; rg < 4; ++rg) {
                                const int xq = mt * 16 + 4 * g + rg;       // x'
                                const int j  = (mt + d) * 16 + c16 - xq;   // w' - x'
                                if (j >= j0 && j < j0 + nj)
                                    ebuf[wid * 1056 + (j - j0) * 96 + 2 * xq + par] =
                                        acc[par][il][mt][d][rg] * scale;
                            }
            }
            __syncthreads();
            const int total = 8 * nj * 96;
            for (int u = tid; u < total; u += 512) {
                const int rgn  = u / (nj * 96);
                const int rem  = u % (nj * 96);
                const int jj   = rem / 96;
                const int x    = rem % 96;
                const int vy_l = rgn & 3;
                const int viy  = iy_base + (rgn >> 2) * 2 + il;
                if (viy < ND)
                    out[(size_t)b * BOUT + (viy * ND + j0 + jj) * CIN +
                        (y0 + vy_l) * 96 + x] = ebuf[rgn * 1056 + jj * 96 + x];
            }
            __syncthreads();
        }
    }
}

extern "C" void kernel_launch(void* const* d_in, const int* in_sizes, int n_in,
                              void* d_out, int out_size, void* d_ws, size_t ws_size,
                              hipStream_t stream) {
    const float* in1 = (const float*)d_in[0];
    const float* in2 = (const float*)d_in[1];
    float* out = (float*)d_out;
    corr_kernel<<<768, 512, 0, stream>>>(in1, in2, out);
}